// Round 6
// baseline (330.723 us; speedup 1.0000x reference)
//
#include <hip/hip_runtime.h>
#include <hip/hip_bf16.h>

#define NV 16384
#define DD 128

typedef __attribute__((ext_vector_type(4))) float f32x4;
typedef __attribute__((ext_vector_type(2))) int i32x2;
typedef long long i64;

#define ASCALE 16384.0f
#define INV_ASCALE (1.0f / 16384.0f)

__device__ __forceinline__ i64 pk8(f32x4 a, f32x4 b, float s) {
  int lo = 0, hi = 0;
  lo = __builtin_amdgcn_cvt_pk_fp8_f32(a[0] * s, a[1] * s, lo, false);
  lo = __builtin_amdgcn_cvt_pk_fp8_f32(a[2] * s, a[3] * s, lo, true);
  hi = __builtin_amdgcn_cvt_pk_fp8_f32(b[0] * s, b[1] * s, hi, false);
  hi = __builtin_amdgcn_cvt_pk_fp8_f32(b[2] * s, b[3] * s, hi, true);
  i32x2 r; r[0] = lo; r[1] = hi;
  return __builtin_bit_cast(i64, r);
}

// ---------------------------------------------------------------------------
// Kernel 1: rwh = h * reg_param[region_index];  ws_ra = rwh@W + bias (f32);
//           tT8 = (rwh@LW) as fp8 e4m3, k-chunk-major blocked layout:
//           [t=NV/64][g8=8][j=128] x 8 bytes
// ---------------------------------------------------------------------------
__global__ __launch_bounds__(128) void k_small(
    const float* __restrict__ h, const int* __restrict__ ridx,
    const float* __restrict__ W, const float* __restrict__ LW,
    const float* __restrict__ RP, const float* __restrict__ bias,
    float* __restrict__ ws_ra, i32x2* __restrict__ tT8)
{
  __shared__ float rwhs[8][DD];
  const int v0 = blockIdx.x * 8;
  const int j  = threadIdx.x;
#pragma unroll
  for (int v = 0; v < 8; ++v) {
    const int i = v0 + v;
    const int r = ridx[i] & 63;
    rwhs[v][j] = h[(size_t)i * DD + j] * RP[r * DD + j];
  }
  __syncthreads();

  float ra[8], tt[8];
  const float bj = bias[j];
#pragma unroll
  for (int v = 0; v < 8; ++v) { ra[v] = bj; tt[v] = 0.f; }

  for (int d = 0; d < DD; d += 4) {
    f32x4 rv[8];
#pragma unroll
    for (int v = 0; v < 8; ++v) rv[v] = *(const f32x4*)&rwhs[v][d];
#pragma unroll
    for (int dd = 0; dd < 4; ++dd) {
      const float w_  = W[(d + dd) * DD + j];
      const float lw_ = LW[(d + dd) * DD + j];
#pragma unroll
      for (int v = 0; v < 8; ++v) {
        ra[v] = fmaf(rv[v][dd], w_,  ra[v]);
        tt[v] = fmaf(rv[v][dd], lw_, tt[v]);
      }
    }
  }
#pragma unroll
  for (int v = 0; v < 8; ++v) ws_ra[(size_t)(v0 + v) * DD + j] = ra[v];

  int lo = 0, hi = 0;
  lo = __builtin_amdgcn_cvt_pk_fp8_f32(tt[0], tt[1], lo, false);
  lo = __builtin_amdgcn_cvt_pk_fp8_f32(tt[2], tt[3], lo, true);
  hi = __builtin_amdgcn_cvt_pk_fp8_f32(tt[4], tt[5], hi, false);
  hi = __builtin_amdgcn_cvt_pk_fp8_f32(tt[6], tt[7], hi, true);
  i32x2 val; val[0] = lo; val[1] = hi;
  tT8[(v0 >> 6) * 1024 + ((v0 >> 3) & 7) * 128 + j] = val;
}

// ---------------------------------------------------------------------------
// Kernel 2: partial rb = adj[rows, khalf] @ t[khalf].  BM=64, BK=64, fp8.
// NO LDS, NO BARRIERS: B fragments loaded straight from global (L2-resident
// by XCD kh-partition swizzle: XCDs 0-3 run kh=0, 4-7 run kh=1, so each
// XCD's L2 caches only its 1MB B-half). A: reg prefetch depth-3 (4 rotating
// sets); B: reg prefetch depth-1 (2 sets). Waves fully decoupled; counted
// vmcnt markers only (steady 24 = A(t+2)+B(t+1)+A(t+3); tail 20/16/0).
// ---------------------------------------------------------------------------
__global__ __launch_bounds__(256, 2) void k_big(
    const float* __restrict__ adj, const unsigned char* __restrict__ tTb,
    float* __restrict__ part)
{
  const int tid  = threadIdx.x;
  const int w    = tid >> 6;
  const int lane = tid & 63;
  const int g    = lane >> 4;
  const int l15  = lane & 15;
  const int h    = blockIdx.x;
  const int kh   = (h & 7) >> 2;              // XCD partition: bid%8<4 -> kh0
  const int mblk = (h >> 3) * 4 + (h & 3);    // bijective remap (512 % 8 == 0)
  const int bid  = mblk * 2 + kh;             // part-buffer slot (same as before)
  const int r0   = mblk * 64;
  const int arow = r0 + w * 16 + l15;
  const float* abase = adj + (size_t)arow * NV + kh * (NV / 2) + g * 8;
  const unsigned char* bbase = tTb + (size_t)kh * 128 * 8192;

  f32x4 acc[8];
#pragma unroll
  for (int f = 0; f < 8; ++f) acc[f] = (f32x4){0.f, 0.f, 0.f, 0.f};

  f32x4 A[4][4];   // 4 rotating A sets, all indices compile-time constant
  i64   Bb[2][16]; // 2 rotating B sets

#define LOADA(S, t) do {                                                       \
    const f32x4* p_ = (const f32x4*)(abase + (size_t)(t) * 64);                \
    A[S][0] = p_[0]; A[S][1] = p_[1];                                          \
    const f32x4* q_ = (const f32x4*)(abase + (size_t)(t) * 64 + 32);           \
    A[S][2] = q_[0]; A[S][3] = q_[1];                                          \
  } while (0)

#define LOADB(S, t) do {                                                       \
    const unsigned char* bt_ = bbase + (size_t)(t) * 8192 + g * 1024 + l15 * 8;\
    _Pragma("unroll")                                                          \
    for (int f_ = 0; f_ < 8; ++f_) {                                           \
      Bb[S][f_]     = *(const i64*)(bt_ + f_ * 128);                           \
      Bb[S][8 + f_] = *(const i64*)(bt_ + 4096 + f_ * 128);                    \
    } } while (0)

#define COMP(AS, BS) do {                                                      \
    const i64 a0_ = pk8(A[AS][0], A[AS][1], ASCALE);                           \
    const i64 a1_ = pk8(A[AS][2], A[AS][3], ASCALE);                           \
    _Pragma("unroll")                                                          \
    for (int f_ = 0; f_ < 8; ++f_) {                                           \
      acc[f_] = __builtin_amdgcn_mfma_f32_16x16x32_fp8_fp8(a0_, Bb[BS][f_],     acc[f_], 0, 0, 0); \
      acc[f_] = __builtin_amdgcn_mfma_f32_16x16x32_fp8_fp8(a1_, Bb[BS][8 + f_], acc[f_], 0, 0, 0); \
    } } while (0)

#define VW(n) asm volatile("s_waitcnt vmcnt(" #n ")" ::: "memory")

  // prologue: A(0),A(1),B(0),A(2) in flight (order matters for vmcnt math)
  LOADA(0, 0);
  LOADA(1, 1);
  LOADB(0, 0);
  LOADA(2, 2);

  for (int tb = 0; tb < 31; ++tb) {
    const int t = tb * 4;
    LOADB(1, t + 1); LOADA(3, t + 3); VW(24); COMP(0, 0);
    LOADB(0, t + 2); LOADA(0, t + 4); VW(24); COMP(1, 1);
    LOADB(1, t + 3); LOADA(1, t + 5); VW(24); COMP(2, 0);
    LOADB(0, t + 4); LOADA(2, t + 6); VW(24); COMP(3, 1);
  }
  // tail: t = 124..127 (A issued through 126, B through 124 on loop exit)
  LOADB(1, 125); LOADA(3, 127); VW(24); COMP(0, 0);   // t=124
  LOADB(0, 126);                VW(20); COMP(1, 1);   // t=125
  LOADB(1, 127);                VW(16); COMP(2, 0);   // t=126
                                VW(0);  COMP(3, 1);   // t=127

#undef LOADA
#undef LOADB
#undef COMP
#undef VW

  // partial write: part[bid][64][128], row=g*4+q, col=f*16+l15 (C/D layout)
  float* pbase = part + ((size_t)bid * 64 + w * 16) * DD;
#pragma unroll
  for (int f = 0; f < 8; ++f) {
    const int col = f * 16 + l15;
#pragma unroll
    for (int q = 0; q < 4; ++q) {
      const int row = g * 4 + q;
      pbase[row * DD + col] = acc[f][q];
    }
  }
}

// ---------------------------------------------------------------------------
// Kernel 3: out = (part0 + part1) * 2^-14 + ws_ra   (deterministic reduce)
// ---------------------------------------------------------------------------
__global__ __launch_bounds__(256) void k_reduce(
    const float* __restrict__ part, const float* __restrict__ ws_ra,
    float* __restrict__ out)
{
  const size_t e = ((size_t)blockIdx.x * 256 + threadIdx.x) * 4;
  const int    mblk  = (int)(e >> 13);
  const int    local = (int)(e & 8191);
  const f32x4 p0 = *(const f32x4*)&part[(size_t)(2 * mblk)     * 8192 + local];
  const f32x4 p1 = *(const f32x4*)&part[(size_t)(2 * mblk + 1) * 8192 + local];
  const f32x4 ra = *(const f32x4*)&ws_ra[e];
  f32x4 o;
#pragma unroll
  for (int i = 0; i < 4; ++i) o[i] = (p0[i] + p1[i]) * INV_ASCALE + ra[i];
  *(f32x4*)&out[e] = o;
}

extern "C" void kernel_launch(void* const* d_in, const int* in_sizes, int n_in,
                              void* d_out, int out_size, void* d_ws, size_t ws_size,
                              hipStream_t stream) {
  const float* h    = (const float*)d_in[0];
  const float* adj  = (const float*)d_in[1];
  const int*   ridx = (const int*)d_in[2];
  const float* W    = (const float*)d_in[3];
  const float* LW   = (const float*)d_in[4];
  const float* RP   = (const float*)d_in[5];
  const float* bias = (const float*)d_in[6];
  float* out = (float*)d_out;

  float* ws_ra = (float*)d_ws;                                    // 8 MB @ 0
  void*  tT8   = (void*)((char*)d_ws + (size_t)8  * 1024 * 1024); // 2 MB @ 8M
  float* part  = (float*)((char*)d_ws + (size_t)16 * 1024 * 1024);// 16 MB @ 16M

  hipLaunchKernelGGL(k_small, dim3(NV / 8), dim3(128), 0, stream,
                     h, ridx, W, LW, RP, bias, ws_ra, (i32x2*)tT8);
  hipLaunchKernelGGL(k_big, dim3(NV / 64 * 2), dim3(256), 0, stream,
                     adj, (const unsigned char*)tT8, part);
  hipLaunchKernelGGL(k_reduce, dim3((NV * DD / 4) / 256), dim3(256), 0, stream,
                     part, ws_ra, out);
}

// Round 7
// 259.339 us; speedup vs baseline: 1.2753x; 1.2753x over previous
//
#include <hip/hip_runtime.h>
#include <hip/hip_bf16.h>

#define NV 16384
#define DD 128

typedef __attribute__((ext_vector_type(4))) float f32x4;
typedef __attribute__((ext_vector_type(2))) int i32x2;
typedef long long i64;

#define ASCALE 16384.0f
#define INV_ASCALE (1.0f / 16384.0f)

__device__ __forceinline__ i64 pk8(f32x4 a, f32x4 b, float s) {
  int lo = 0, hi = 0;
  lo = __builtin_amdgcn_cvt_pk_fp8_f32(a[0] * s, a[1] * s, lo, false);
  lo = __builtin_amdgcn_cvt_pk_fp8_f32(a[2] * s, a[3] * s, lo, true);
  hi = __builtin_amdgcn_cvt_pk_fp8_f32(b[0] * s, b[1] * s, hi, false);
  hi = __builtin_amdgcn_cvt_pk_fp8_f32(b[2] * s, b[3] * s, hi, true);
  i32x2 r; r[0] = lo; r[1] = hi;
  return __builtin_bit_cast(i64, r);
}

// ---------------------------------------------------------------------------
// Kernel 1: rwh = h * reg_param[region_index];  ws_ra = rwh@W + bias (f32);
//           tT8 = (rwh@LW) as fp8 e4m3, k-chunk-major blocked layout:
//           [t=NV/64][g8=8][j=128] x 8 bytes
// ---------------------------------------------------------------------------
__global__ __launch_bounds__(128) void k_small(
    const float* __restrict__ h, const int* __restrict__ ridx,
    const float* __restrict__ W, const float* __restrict__ LW,
    const float* __restrict__ RP, const float* __restrict__ bias,
    float* __restrict__ ws_ra, i32x2* __restrict__ tT8)
{
  __shared__ float rwhs[8][DD];
  const int v0 = blockIdx.x * 8;
  const int j  = threadIdx.x;
#pragma unroll
  for (int v = 0; v < 8; ++v) {
    const int i = v0 + v;
    const int r = ridx[i] & 63;
    rwhs[v][j] = h[(size_t)i * DD + j] * RP[r * DD + j];
  }
  __syncthreads();

  float ra[8], tt[8];
  const float bj = bias[j];
#pragma unroll
  for (int v = 0; v < 8; ++v) { ra[v] = bj; tt[v] = 0.f; }

  for (int d = 0; d < DD; d += 4) {
    f32x4 rv[8];
#pragma unroll
    for (int v = 0; v < 8; ++v) rv[v] = *(const f32x4*)&rwhs[v][d];
#pragma unroll
    for (int dd = 0; dd < 4; ++dd) {
      const float w_  = W[(d + dd) * DD + j];
      const float lw_ = LW[(d + dd) * DD + j];
#pragma unroll
      for (int v = 0; v < 8; ++v) {
        ra[v] = fmaf(rv[v][dd], w_,  ra[v]);
        tt[v] = fmaf(rv[v][dd], lw_, tt[v]);
      }
    }
  }
#pragma unroll
  for (int v = 0; v < 8; ++v) ws_ra[(size_t)(v0 + v) * DD + j] = ra[v];

  int lo = 0, hi = 0;
  lo = __builtin_amdgcn_cvt_pk_fp8_f32(tt[0], tt[1], lo, false);
  lo = __builtin_amdgcn_cvt_pk_fp8_f32(tt[2], tt[3], lo, true);
  hi = __builtin_amdgcn_cvt_pk_fp8_f32(tt[4], tt[5], hi, false);
  hi = __builtin_amdgcn_cvt_pk_fp8_f32(tt[6], tt[7], hi, true);
  i32x2 val; val[0] = lo; val[1] = hi;
  tT8[(v0 >> 6) * 1024 + ((v0 >> 3) & 7) * 128 + j] = val;
}

// ---------------------------------------------------------------------------
// Kernel 2: partial rb = adj[rows, khalf] @ t[khalf].  BM=64, BK=128, fp8.
// Round-5 structure (LDS B staging + 1 barrier/iter + counted vmcnt) with:
//  * BK=128: 64 iters (half the barriers), 512B/row/tile A bursts, ~1-1.5KB
//    per row-stream in flight -> DRAM row-buffer batching (H2')
//  * XCD kh-partition swizzle: XCDs 0-3 do kh=0, 4-7 do kh=1 -> each XCD L2
//    holds only its 1MB B half -> no B re-fetch from HBM (H6)
// A: 2 rotating reg sets (LOADA after COMP -> no WAR); B: 4x16KB LDS bufs.
// vmcnt: 12 ops/tile (4 stage + 8 A); steady VW(12), tail 12/0.
// ---------------------------------------------------------------------------
__global__ __launch_bounds__(256, 2) void k_big(
    const float* __restrict__ adj, const unsigned char* __restrict__ tTb,
    float* __restrict__ part)
{
  __shared__ unsigned char Bs[4][16384] __attribute__((aligned(16)));
  const int tid  = threadIdx.x;
  const int w    = tid >> 6;
  const int lane = tid & 63;
  const int g    = lane >> 4;
  const int l15  = lane & 15;
  const int hb   = blockIdx.x;
  const int kh   = (hb & 7) >> 2;             // XCD partition: bid%8<4 -> kh0
  const int mblk = (hb >> 3) * 4 + (hb & 3);  // bijective remap (512 % 8 == 0)
  const int bid  = mblk * 2 + kh;             // part-buffer slot
  const int r0   = mblk * 64;
  const int arow = r0 + w * 16 + l15;
  const float* abase = adj + (size_t)arow * NV + kh * (NV / 2) + g * 8;
  const unsigned char* bbase = tTb + (size_t)kh * 128 * 8192;

  f32x4 acc[8];
#pragma unroll
  for (int f = 0; f < 8; ++f) acc[f] = (f32x4){0.f, 0.f, 0.f, 0.f};

  f32x4 A0[8], A1[8];   // 2 rotating A sets (t even -> A0, t odd -> A1)

#define STAGE(t) do {                                                          \
    const int buf_ = (t) & 3;                                                  \
    _Pragma("unroll")                                                          \
    for (int i_ = 0; i_ < 4; ++i_) {                                           \
      const int unit_ = i_ * 4 + w;            /* 0..15, wave-uniform */       \
      const unsigned char* src_ = bbase + (size_t)(t) * 16384 +                \
                                  unit_ * 1024 + lane * 16;                    \
      __builtin_amdgcn_global_load_lds(                                        \
          (const __attribute__((address_space(1))) unsigned int*)src_,         \
          (__attribute__((address_space(3))) unsigned int*)&Bs[buf_][unit_ * 1024], \
          16, 0, 0);                                                           \
    } } while (0)

#define LOADA(AS, t) do {                                                      \
    _Pragma("unroll")                                                          \
    for (int s_ = 0; s_ < 4; ++s_) {                                           \
      const f32x4* p_ = (const f32x4*)(abase + (size_t)(t) * 128 + s_ * 32);   \
      AS[2 * s_]     = p_[0];                                                  \
      AS[2 * s_ + 1] = p_[1];                                                  \
    } } while (0)

#define COMP(AS, t) do {                                                       \
    const int buf_ = (t) & 3;                                                  \
    const i64 a0_ = pk8(AS[0], AS[1], ASCALE);                                 \
    const i64 a1_ = pk8(AS[2], AS[3], ASCALE);                                 \
    const i64 a2_ = pk8(AS[4], AS[5], ASCALE);                                 \
    const i64 a3_ = pk8(AS[6], AS[7], ASCALE);                                 \
    _Pragma("unroll")                                                          \
    for (int f_ = 0; f_ < 8; ++f_) {                                           \
      const int jr8_ = (f_ * 16 + l15) * 8;                                    \
      acc[f_] = __builtin_amdgcn_mfma_f32_16x16x32_fp8_fp8(a0_,                \
          *(const i64*)&Bs[buf_][g * 1024 + jr8_],            acc[f_], 0, 0, 0); \
      acc[f_] = __builtin_amdgcn_mfma_f32_16x16x32_fp8_fp8(a1_,                \
          *(const i64*)&Bs[buf_][(4 + g) * 1024 + jr8_],      acc[f_], 0, 0, 0); \
      acc[f_] = __builtin_amdgcn_mfma_f32_16x16x32_fp8_fp8(a2_,                \
          *(const i64*)&Bs[buf_][8192 + g * 1024 + jr8_],     acc[f_], 0, 0, 0); \
      acc[f_] = __builtin_amdgcn_mfma_f32_16x16x32_fp8_fp8(a3_,                \
          *(const i64*)&Bs[buf_][8192 + (4 + g) * 1024 + jr8_], acc[f_], 0, 0, 0); \
    } } while (0)

#define VW12 asm volatile("s_waitcnt vmcnt(12)" ::: "memory")
#define VW0  asm volatile("s_waitcnt vmcnt(0)"  ::: "memory")
#define BAR  __builtin_amdgcn_s_barrier()

  // prologue: tiles 0,1 in flight (12 ops each, tile-contiguous)
  STAGE(0); LOADA(A0, 0);
  STAGE(1); LOADA(A1, 1);

  // steady: iters 0..61 (pairs); LOADA after COMP -> 2 reg sets suffice
  for (int tp = 0; tp < 31; ++tp) {
    const int t = tp * 2;
    VW12; BAR; STAGE(t + 2); COMP(A0, t);     LOADA(A0, t + 2);
    VW12; BAR; STAGE(t + 3); COMP(A1, t + 1); LOADA(A1, t + 3);
  }
  // tail: iters 62, 63
  VW12; BAR; COMP(A0, 62);
  VW0;  BAR; COMP(A1, 63);

#undef STAGE
#undef LOADA
#undef COMP
#undef VW12
#undef VW0
#undef BAR

  // partial write: part[bid][64][128], row=g*4+q, col=f*16+l15 (C/D layout)
  float* pbase = part + ((size_t)bid * 64 + w * 16) * DD;
#pragma unroll
  for (int f = 0; f < 8; ++f) {
    const int col = f * 16 + l15;
#pragma unroll
    for (int q = 0; q < 4; ++q) {
      const int row = g * 4 + q;
      pbase[row * DD + col] = acc[f][q];
    }
  }
}

// ---------------------------------------------------------------------------
// Kernel 3: out = (part0 + part1) * 2^-14 + ws_ra   (deterministic reduce)
// ---------------------------------------------------------------------------
__global__ __launch_bounds__(256) void k_reduce(
    const float* __restrict__ part, const float* __restrict__ ws_ra,
    float* __restrict__ out)
{
  const size_t e = ((size_t)blockIdx.x * 256 + threadIdx.x) * 4;
  const int    mblk  = (int)(e >> 13);
  const int    local = (int)(e & 8191);
  const f32x4 p0 = *(const f32x4*)&part[(size_t)(2 * mblk)     * 8192 + local];
  const f32x4 p1 = *(const f32x4*)&part[(size_t)(2 * mblk + 1) * 8192 + local];
  const f32x4 ra = *(const f32x4*)&ws_ra[e];
  f32x4 o;
#pragma unroll
  for (int i = 0; i < 4; ++i) o[i] = (p0[i] + p1[i]) * INV_ASCALE + ra[i];
  *(f32x4*)&out[e] = o;
}

extern "C" void kernel_launch(void* const* d_in, const int* in_sizes, int n_in,
                              void* d_out, int out_size, void* d_ws, size_t ws_size,
                              hipStream_t stream) {
  const float* h    = (const float*)d_in[0];
  const float* adj  = (const float*)d_in[1];
  const int*   ridx = (const int*)d_in[2];
  const float* W    = (const float*)d_in[3];
  const float* LW   = (const float*)d_in[4];
  const float* RP   = (const float*)d_in[5];
  const float* bias = (const float*)d_in[6];
  float* out = (float*)d_out;

  float* ws_ra = (float*)d_ws;                                    // 8 MB @ 0
  void*  tT8   = (void*)((char*)d_ws + (size_t)8  * 1024 * 1024); // 2 MB @ 8M
  float* part  = (float*)((char*)d_ws + (size_t)16 * 1024 * 1024);// 16 MB @ 16M

  hipLaunchKernelGGL(k_small, dim3(NV / 8), dim3(128), 0, stream,
                     h, ridx, W, LW, RP, bias, ws_ra, (i32x2*)tT8);
  hipLaunchKernelGGL(k_big, dim3(NV / 64 * 2), dim3(256), 0, stream,
                     adj, (const unsigned char*)tT8, part);
  hipLaunchKernelGGL(k_reduce, dim3((NV * DD / 4) / 256), dim3(256), 0, stream,
                     part, ws_ra, out);
}

// Round 8
// 238.395 us; speedup vs baseline: 1.3873x; 1.0879x over previous
//
#include <hip/hip_runtime.h>
#include <hip/hip_bf16.h>

#define NV 16384
#define DD 128

typedef __attribute__((ext_vector_type(4))) float f32x4;
typedef __attribute__((ext_vector_type(2))) int i32x2;
typedef long long i64;

#define ASCALE 16384.0f
#define INV_ASCALE (1.0f / 16384.0f)

__device__ __forceinline__ i64 pk8(f32x4 a, f32x4 b, float s) {
  int lo = 0, hi = 0;
  lo = __builtin_amdgcn_cvt_pk_fp8_f32(a[0] * s, a[1] * s, lo, false);
  lo = __builtin_amdgcn_cvt_pk_fp8_f32(a[2] * s, a[3] * s, lo, true);
  hi = __builtin_amdgcn_cvt_pk_fp8_f32(b[0] * s, b[1] * s, hi, false);
  hi = __builtin_amdgcn_cvt_pk_fp8_f32(b[2] * s, b[3] * s, hi, true);
  i32x2 r; r[0] = lo; r[1] = hi;
  return __builtin_bit_cast(i64, r);
}

// ---------------------------------------------------------------------------
// Kernel 1: rwh = h * reg_param[region_index];  ws_ra = rwh@W + bias (f32);
//           tT8 = (rwh@LW) as fp8 e4m3, k-chunk-major blocked layout:
//           [t=NV/64][g8=8][j=128] x 8 bytes
// ---------------------------------------------------------------------------
__global__ __launch_bounds__(128) void k_small(
    const float* __restrict__ h, const int* __restrict__ ridx,
    const float* __restrict__ W, const float* __restrict__ LW,
    const float* __restrict__ RP, const float* __restrict__ bias,
    float* __restrict__ ws_ra, i32x2* __restrict__ tT8)
{
  __shared__ float rwhs[8][DD];
  const int v0 = blockIdx.x * 8;
  const int j  = threadIdx.x;
#pragma unroll
  for (int v = 0; v < 8; ++v) {
    const int i = v0 + v;
    const int r = ridx[i] & 63;
    rwhs[v][j] = h[(size_t)i * DD + j] * RP[r * DD + j];
  }
  __syncthreads();

  float ra[8], tt[8];
  const float bj = bias[j];
#pragma unroll
  for (int v = 0; v < 8; ++v) { ra[v] = bj; tt[v] = 0.f; }

  for (int d = 0; d < DD; d += 4) {
    f32x4 rv[8];
#pragma unroll
    for (int v = 0; v < 8; ++v) rv[v] = *(const f32x4*)&rwhs[v][d];
#pragma unroll
    for (int dd = 0; dd < 4; ++dd) {
      const float w_  = W[(d + dd) * DD + j];
      const float lw_ = LW[(d + dd) * DD + j];
#pragma unroll
      for (int v = 0; v < 8; ++v) {
        ra[v] = fmaf(rv[v][dd], w_,  ra[v]);
        tt[v] = fmaf(rv[v][dd], lw_, tt[v]);
      }
    }
  }
#pragma unroll
  for (int v = 0; v < 8; ++v) ws_ra[(size_t)(v0 + v) * DD + j] = ra[v];

  int lo = 0, hi = 0;
  lo = __builtin_amdgcn_cvt_pk_fp8_f32(tt[0], tt[1], lo, false);
  lo = __builtin_amdgcn_cvt_pk_fp8_f32(tt[2], tt[3], lo, true);
  hi = __builtin_amdgcn_cvt_pk_fp8_f32(tt[4], tt[5], hi, false);
  hi = __builtin_amdgcn_cvt_pk_fp8_f32(tt[6], tt[7], hi, true);
  i32x2 val; val[0] = lo; val[1] = hi;
  tT8[(v0 >> 6) * 1024 + ((v0 >> 3) & 7) * 128 + j] = val;
}

// ---------------------------------------------------------------------------
// Kernel 2: partial rb = adj[rows, khalf] @ t[khalf].  BM=64, BK=128, fp8.
// R7 structure + PER-BLOCK K-ROTATION: block mblk starts its tile walk at
// t0 = mblk & 63 and wraps mod 64.  adj rows are 64KB apart, so a line's
// HBM channel is determined purely by its k-offset; without rotation all
// blocks sweep the same k-window in lockstep -> channel concentration.
// Rotation spreads the 256 blocks/half uniformly over all 64 tile slots.
// Register accumulation makes per-block start order irrelevant (and fixed
// -> deterministic).  Pipeline slots (LDS buf, vmcnt) use logical t; only
// the address mapping RT(t) rotates.
// ---------------------------------------------------------------------------
__global__ __launch_bounds__(256, 2) void k_big(
    const float* __restrict__ adj, const unsigned char* __restrict__ tTb,
    float* __restrict__ part)
{
  __shared__ unsigned char Bs[4][16384] __attribute__((aligned(16)));
  const int tid  = threadIdx.x;
  const int w    = tid >> 6;
  const int lane = tid & 63;
  const int g    = lane >> 4;
  const int l15  = lane & 15;
  const int hb   = blockIdx.x;
  const int kh   = (hb & 7) >> 2;             // XCD partition: bid%8<4 -> kh0
  const int mblk = (hb >> 3) * 4 + (hb & 3);  // bijective remap (512 % 8 == 0)
  const int bid  = mblk * 2 + kh;             // part-buffer slot
  const int r0   = mblk * 64;
  const int t0   = mblk & 63;                 // K-rotation start tile
  const int arow = r0 + w * 16 + l15;
  const float* abase = adj + (size_t)arow * NV + kh * (NV / 2) + g * 8;
  const unsigned char* bbase = tTb + (size_t)kh * 128 * 8192;

#define RT(t) ((t0 + (t)) & 63)

  f32x4 acc[8];
#pragma unroll
  for (int f = 0; f < 8; ++f) acc[f] = (f32x4){0.f, 0.f, 0.f, 0.f};

  f32x4 A0[8], A1[8];   // 2 rotating A sets (logical t even -> A0, odd -> A1)

#define STAGE(slot, rt) do {                                                   \
    const int buf_ = (slot) & 3;                                               \
    _Pragma("unroll")                                                          \
    for (int i_ = 0; i_ < 4; ++i_) {                                           \
      const int unit_ = i_ * 4 + w;            /* 0..15, wave-uniform */       \
      const unsigned char* src_ = bbase + (size_t)(rt) * 16384 +               \
                                  unit_ * 1024 + lane * 16;                    \
      __builtin_amdgcn_global_load_lds(                                        \
          (const __attribute__((address_space(1))) unsigned int*)src_,         \
          (__attribute__((address_space(3))) unsigned int*)&Bs[buf_][unit_ * 1024], \
          16, 0, 0);                                                           \
    } } while (0)

#define LOADA(AS, rt) do {                                                     \
    _Pragma("unroll")                                                          \
    for (int s_ = 0; s_ < 4; ++s_) {                                           \
      const f32x4* p_ = (const f32x4*)(abase + (size_t)(rt) * 128 + s_ * 32);  \
      AS[2 * s_]     = p_[0];                                                  \
      AS[2 * s_ + 1] = p_[1];                                                  \
    } } while (0)

#define COMP(AS, slot) do {                                                    \
    const int buf_ = (slot) & 3;                                               \
    const i64 a0_ = pk8(AS[0], AS[1], ASCALE);                                 \
    const i64 a1_ = pk8(AS[2], AS[3], ASCALE);                                 \
    const i64 a2_ = pk8(AS[4], AS[5], ASCALE);                                 \
    const i64 a3_ = pk8(AS[6], AS[7], ASCALE);                                 \
    _Pragma("unroll")                                                          \
    for (int f_ = 0; f_ < 8; ++f_) {                                           \
      const int jr8_ = (f_ * 16 + l15) * 8;                                    \
      acc[f_] = __builtin_amdgcn_mfma_f32_16x16x32_fp8_fp8(a0_,                \
          *(const i64*)&Bs[buf_][g * 1024 + jr8_],            acc[f_], 0, 0, 0); \
      acc[f_] = __builtin_amdgcn_mfma_f32_16x16x32_fp8_fp8(a1_,                \
          *(const i64*)&Bs[buf_][(4 + g) * 1024 + jr8_],      acc[f_], 0, 0, 0); \
      acc[f_] = __builtin_amdgcn_mfma_f32_16x16x32_fp8_fp8(a2_,                \
          *(const i64*)&Bs[buf_][8192 + g * 1024 + jr8_],     acc[f_], 0, 0, 0); \
      acc[f_] = __builtin_amdgcn_mfma_f32_16x16x32_fp8_fp8(a3_,                \
          *(const i64*)&Bs[buf_][8192 + (4 + g) * 1024 + jr8_], acc[f_], 0, 0, 0); \
    } } while (0)

#define VW12 asm volatile("s_waitcnt vmcnt(12)" ::: "memory")
#define VW0  asm volatile("s_waitcnt vmcnt(0)"  ::: "memory")
#define BAR  __builtin_amdgcn_s_barrier()

  // prologue: logical tiles 0,1 in flight (12 ops each, tile-contiguous)
  STAGE(0, RT(0)); LOADA(A0, RT(0));
  STAGE(1, RT(1)); LOADA(A1, RT(1));

  // steady: logical iters 0..61 (pairs); LOADA after COMP -> 2 reg sets ok
  for (int tp = 0; tp < 31; ++tp) {
    const int t = tp * 2;
    VW12; BAR; STAGE(t + 2, RT(t + 2)); COMP(A0, t);     LOADA(A0, RT(t + 2));
    VW12; BAR; STAGE(t + 3, RT(t + 3)); COMP(A1, t + 1); LOADA(A1, RT(t + 3));
  }
  // tail: logical iters 62, 63
  VW12; BAR; COMP(A0, 62);
  VW0;  BAR; COMP(A1, 63);

#undef STAGE
#undef LOADA
#undef COMP
#undef VW12
#undef VW0
#undef BAR
#undef RT

  // partial write: part[bid][64][128], row=g*4+q, col=f*16+l15 (C/D layout)
  float* pbase = part + ((size_t)bid * 64 + w * 16) * DD;
#pragma unroll
  for (int f = 0; f < 8; ++f) {
    const int col = f * 16 + l15;
#pragma unroll
    for (int q = 0; q < 4; ++q) {
      const int row = g * 4 + q;
      pbase[row * DD + col] = acc[f][q];
    }
  }
}

// ---------------------------------------------------------------------------
// Kernel 3: out = (part0 + part1) * 2^-14 + ws_ra   (deterministic reduce)
// ---------------------------------------------------------------------------
__global__ __launch_bounds__(256) void k_reduce(
    const float* __restrict__ part, const float* __restrict__ ws_ra,
    float* __restrict__ out)
{
  const size_t e = ((size_t)blockIdx.x * 256 + threadIdx.x) * 4;
  const int    mblk  = (int)(e >> 13);
  const int    local = (int)(e & 8191);
  const f32x4 p0 = *(const f32x4*)&part[(size_t)(2 * mblk)     * 8192 + local];
  const f32x4 p1 = *(const f32x4*)&part[(size_t)(2 * mblk + 1) * 8192 + local];
  const f32x4 ra = *(const f32x4*)&ws_ra[e];
  f32x4 o;
#pragma unroll
  for (int i = 0; i < 4; ++i) o[i] = (p0[i] + p1[i]) * INV_ASCALE + ra[i];
  *(f32x4*)&out[e] = o;
}

extern "C" void kernel_launch(void* const* d_in, const int* in_sizes, int n_in,
                              void* d_out, int out_size, void* d_ws, size_t ws_size,
                              hipStream_t stream) {
  const float* h    = (const float*)d_in[0];
  const float* adj  = (const float*)d_in[1];
  const int*   ridx = (const int*)d_in[2];
  const float* W    = (const float*)d_in[3];
  const float* LW   = (const float*)d_in[4];
  const float* RP   = (const float*)d_in[5];
  const float* bias = (const float*)d_in[6];
  float* out = (float*)d_out;

  float* ws_ra = (float*)d_ws;                                    // 8 MB @ 0
  void*  tT8   = (void*)((char*)d_ws + (size_t)8  * 1024 * 1024); // 2 MB @ 8M
  float* part  = (float*)((char*)d_ws + (size_t)16 * 1024 * 1024);// 16 MB @ 16M

  hipLaunchKernelGGL(k_small, dim3(NV / 8), dim3(128), 0, stream,
                     h, ridx, W, LW, RP, bias, ws_ra, (i32x2*)tT8);
  hipLaunchKernelGGL(k_big, dim3(NV / 64 * 2), dim3(256), 0, stream,
                     adj, (const unsigned char*)tT8, part);
  hipLaunchKernelGGL(k_reduce, dim3((NV * DD / 4) / 256), dim3(256), 0, stream,
                     part, ws_ra, out);
}

// Round 9
// 228.902 us; speedup vs baseline: 1.4448x; 1.0415x over previous
//
#include <hip/hip_runtime.h>
#include <hip/hip_bf16.h>

#define NV 16384
#define DD 128

typedef __attribute__((ext_vector_type(8))) short bf16x8;
typedef __attribute__((ext_vector_type(8))) unsigned short ushort8v;
typedef __attribute__((ext_vector_type(4))) float f32x4;
typedef __attribute__((ext_vector_type(2))) int i32x2;
typedef long long i64;

#define ASCALE 16384.0f
#define INV_ASCALE (1.0f / 16384.0f)

__device__ __forceinline__ unsigned short f2bf(float x) {
  unsigned u = __builtin_bit_cast(unsigned, x);
  u = (u + 0x7FFFu + ((u >> 16) & 1u)) >> 16;   // round-to-nearest-even
  return (unsigned short)u;
}

__device__ __forceinline__ i64 pk8(f32x4 a, f32x4 b, float s) {
  int lo = 0, hi = 0;
  lo = __builtin_amdgcn_cvt_pk_fp8_f32(a[0] * s, a[1] * s, lo, false);
  lo = __builtin_amdgcn_cvt_pk_fp8_f32(a[2] * s, a[3] * s, lo, true);
  hi = __builtin_amdgcn_cvt_pk_fp8_f32(b[0] * s, b[1] * s, hi, false);
  hi = __builtin_amdgcn_cvt_pk_fp8_f32(b[2] * s, b[3] * s, hi, true);
  i32x2 r; r[0] = lo; r[1] = hi;
  return __builtin_bit_cast(i64, r);
}

// ---------------------------------------------------------------------------
// Kernel 1 (MFMA rewrite): per block of 64 vertices:
//  phase 0: stage W^T, LW^T as bf16 in LDS (chunk-XOR swizzled), from the
//           64KB global weights (L2/L3-hot after first touch)
//  phase 1: rwh = h * reg_param[region_index(int64!)] -> bf16 LDS, swizzled
//  phase 2: dual-GEMM via mfma_f32_16x16x32_bf16, N=256 fused (ra | t)
//  phase 3: ra + bias -> ws_ra (f32); t -> fp8 e4m3 tT8 chunks (shfl_xor
//           pairs g<->g+1 to build 8-vertex chunks)
// tT8 layout unchanged: [v>>6][ (v>>3)&7 ][ j ] x 8 bytes.
// ---------------------------------------------------------------------------
__global__ __launch_bounds__(256) void k_small(
    const float* __restrict__ h, const long long* __restrict__ ridx,
    const float* __restrict__ W, const float* __restrict__ LW,
    const float* __restrict__ RP, const float* __restrict__ bias,
    float* __restrict__ ws_ra, i32x2* __restrict__ tT8)
{
  __shared__ unsigned short rw [64 * 128];    // 16 KB rwh bf16, swizzled
  __shared__ unsigned short Wts[128 * 128];   // 32 KB W^T bf16, swizzled
  __shared__ unsigned short LWts[128 * 128];  // 32 KB LW^T bf16, swizzled
  const int tid = threadIdx.x;
  const int r0  = blockIdx.x * 64;

  // ---- phase 0: weights -> LDS transposed+swizzled ----
  {
    const int k  = tid >> 1;            // 0..127
    const int j0 = (tid & 1) * 64;      // j half
    const float* wr  = W  + k * DD + j0;
    const float* lwr = LW + k * DD + j0;
#pragma unroll 8
    for (int i = 0; i < 64; ++i) {
      const int j = j0 + i;
      const int off = j * 128 + (((k >> 3) ^ (j & 7)) << 3) + (k & 7);
      Wts [off] = f2bf(wr[i]);
      LWts[off] = f2bf(lwr[i]);
    }
  }

  // ---- phase 1: rwh bf16 -> LDS swizzled ----
  {
    const int r  = tid >> 2;            // 0..63
    const int cc = tid & 3;             // 32-col chunk-quad
    const int v  = r0 + r;
    const int reg = ((int)ridx[v]) & 63;
    const float* hp = h  + (size_t)v * DD + cc * 32;
    const float* rp = RP + reg * DD + cc * 32;
#pragma unroll
    for (int i = 0; i < 4; ++i) {
      const f32x4 a  = *(const f32x4*)(hp + i * 8);
      const f32x4 b  = *(const f32x4*)(hp + i * 8 + 4);
      const f32x4 pa = *(const f32x4*)(rp + i * 8);
      const f32x4 pb = *(const f32x4*)(rp + i * 8 + 4);
      ushort8v pk;
#pragma unroll
      for (int q = 0; q < 4; ++q) {
        pk[q]     = f2bf(a[q] * pa[q]);
        pk[4 + q] = f2bf(b[q] * pb[q]);
      }
      const int sc = (cc * 4 + i) ^ (r & 7);
      *(ushort8v*)&rw[r * 128 + sc * 8] = pk;
    }
  }
  __syncthreads();

  // ---- phase 2: MFMA dual-GEMM ----
  const int w = tid >> 6, lane = tid & 63, g = lane >> 4, l15 = lane & 15;
  f32x4 accA[8], accT[8];
#pragma unroll
  for (int f = 0; f < 8; ++f) {
    accA[f] = (f32x4){0.f, 0.f, 0.f, 0.f};
    accT[f] = (f32x4){0.f, 0.f, 0.f, 0.f};
  }
  const int arow = w * 16 + l15;
#pragma unroll
  for (int s = 0; s < 4; ++s) {
    const int sca = (s * 4 + g) ^ (l15 & 7);   // (arow&7)==l15&7
    const bf16x8 af = *(const bf16x8*)&rw[arow * 128 + sca * 8];
#pragma unroll
    for (int f = 0; f < 8; ++f) {
      const int j = f * 16 + l15;
      const int scb = (s * 4 + g) ^ (l15 & 7); // (j&7)==l15&7
      const bf16x8 bw = *(const bf16x8*)&Wts [j * 128 + scb * 8];
      accA[f] = __builtin_amdgcn_mfma_f32_16x16x32_bf16(af, bw, accA[f], 0, 0, 0);
      const bf16x8 bl = *(const bf16x8*)&LWts[j * 128 + scb * 8];
      accT[f] = __builtin_amdgcn_mfma_f32_16x16x32_bf16(af, bl, accT[f], 0, 0, 0);
    }
  }

  // ---- phase 3a: ra + bias -> ws_ra ----
#pragma unroll
  for (int f = 0; f < 8; ++f) {
    const int col = f * 16 + l15;
    const float bj = bias[col];
#pragma unroll
    for (int q = 0; q < 4; ++q) {
      const int v = r0 + w * 16 + g * 4 + q;
      ws_ra[(size_t)v * DD + col] = accA[f][q] + bj;
    }
  }
  // ---- phase 3b: t -> fp8 chunks (pair lanes g, g+1 via shfl_xor 16) ----
#pragma unroll
  for (int f = 0; f < 8; ++f) {
    const int j = f * 16 + l15;
    int own = 0;
    own = __builtin_amdgcn_cvt_pk_fp8_f32(accT[f][0], accT[f][1], own, false);
    own = __builtin_amdgcn_cvt_pk_fp8_f32(accT[f][2], accT[f][3], own, true);
    const int partner = __shfl_xor(own, 16, 64);
    if ((g & 1) == 0) {
      const int v0 = r0 + w * 16 + g * 4;      // multiple of 8
      i32x2 val; val[0] = own; val[1] = partner;
      tT8[(v0 >> 6) * 1024 + ((v0 >> 3) & 7) * 128 + j] = val;
    }
  }
}

// ---------------------------------------------------------------------------
// Kernel 2: partial rb = adj[rows, khalf] @ t[khalf].  BM=64, BK=128, fp8.
// (unchanged from round 8: K-rotation + XCD kh-partition + counted vmcnt)
// ---------------------------------------------------------------------------
__global__ __launch_bounds__(256, 2) void k_big(
    const float* __restrict__ adj, const unsigned char* __restrict__ tTb,
    float* __restrict__ part)
{
  __shared__ unsigned char Bs[4][16384] __attribute__((aligned(16)));
  const int tid  = threadIdx.x;
  const int w    = tid >> 6;
  const int lane = tid & 63;
  const int g    = lane >> 4;
  const int l15  = lane & 15;
  const int hb   = blockIdx.x;
  const int kh   = (hb & 7) >> 2;             // XCD partition: bid%8<4 -> kh0
  const int mblk = (hb >> 3) * 4 + (hb & 3);  // bijective remap (512 % 8 == 0)
  const int bid  = mblk * 2 + kh;             // part-buffer slot
  const int r0   = mblk * 64;
  const int t0   = mblk & 63;                 // K-rotation start tile
  const int arow = r0 + w * 16 + l15;
  const float* abase = adj + (size_t)arow * NV + kh * (NV / 2) + g * 8;
  const unsigned char* bbase = tTb + (size_t)kh * 128 * 8192;

#define RT(t) ((t0 + (t)) & 63)

  f32x4 acc[8];
#pragma unroll
  for (int f = 0; f < 8; ++f) acc[f] = (f32x4){0.f, 0.f, 0.f, 0.f};

  f32x4 A0[8], A1[8];

#define STAGE(slot, rt) do {                                                   \
    const int buf_ = (slot) & 3;                                               \
    _Pragma("unroll")                                                          \
    for (int i_ = 0; i_ < 4; ++i_) {                                           \
      const int unit_ = i_ * 4 + w;                                            \
      const unsigned char* src_ = bbase + (size_t)(rt) * 16384 +               \
                                  unit_ * 1024 + lane * 16;                    \
      __builtin_amdgcn_global_load_lds(                                        \
          (const __attribute__((address_space(1))) unsigned int*)src_,         \
          (__attribute__((address_space(3))) unsigned int*)&Bs[buf_][unit_ * 1024], \
          16, 0, 0);                                                           \
    } } while (0)

#define LOADA(AS, rt) do {                                                     \
    _Pragma("unroll")                                                          \
    for (int s_ = 0; s_ < 4; ++s_) {                                           \
      const f32x4* p_ = (const f32x4*)(abase + (size_t)(rt) * 128 + s_ * 32);  \
      AS[2 * s_]     = p_[0];                                                  \
      AS[2 * s_ + 1] = p_[1];                                                  \
    } } while (0)

#define COMP(AS, slot) do {                                                    \
    const int buf_ = (slot) & 3;                                               \
    const i64 a0_ = pk8(AS[0], AS[1], ASCALE);                                 \
    const i64 a1_ = pk8(AS[2], AS[3], ASCALE);                                 \
    const i64 a2_ = pk8(AS[4], AS[5], ASCALE);                                 \
    const i64 a3_ = pk8(AS[6], AS[7], ASCALE);                                 \
    _Pragma("unroll")                                                          \
    for (int f_ = 0; f_ < 8; ++f_) {                                           \
      const int jr8_ = (f_ * 16 + l15) * 8;                                    \
      acc[f_] = __builtin_amdgcn_mfma_f32_16x16x32_fp8_fp8(a0_,                \
          *(const i64*)&Bs[buf_][g * 1024 + jr8_],            acc[f_], 0, 0, 0); \
      acc[f_] = __builtin_amdgcn_mfma_f32_16x16x32_fp8_fp8(a1_,                \
          *(const i64*)&Bs[buf_][(4 + g) * 1024 + jr8_],      acc[f_], 0, 0, 0); \
      acc[f_] = __builtin_amdgcn_mfma_f32_16x16x32_fp8_fp8(a2_,                \
          *(const i64*)&Bs[buf_][8192 + g * 1024 + jr8_],     acc[f_], 0, 0, 0); \
      acc[f_] = __builtin_amdgcn_mfma_f32_16x16x32_fp8_fp8(a3_,                \
          *(const i64*)&Bs[buf_][8192 + (4 + g) * 1024 + jr8_], acc[f_], 0, 0, 0); \
    } } while (0)

#define VW12 asm volatile("s_waitcnt vmcnt(12)" ::: "memory")
#define VW0  asm volatile("s_waitcnt vmcnt(0)"  ::: "memory")
#define BAR  __builtin_amdgcn_s_barrier()

  STAGE(0, RT(0)); LOADA(A0, RT(0));
  STAGE(1, RT(1)); LOADA(A1, RT(1));

  for (int tp = 0; tp < 31; ++tp) {
    const int t = tp * 2;
    VW12; BAR; STAGE(t + 2, RT(t + 2)); COMP(A0, t);     LOADA(A0, RT(t + 2));
    VW12; BAR; STAGE(t + 3, RT(t + 3)); COMP(A1, t + 1); LOADA(A1, RT(t + 3));
  }
  VW12; BAR; COMP(A0, 62);
  VW0;  BAR; COMP(A1, 63);

#undef STAGE
#undef LOADA
#undef COMP
#undef VW12
#undef VW0
#undef BAR
#undef RT

  float* pbase = part + ((size_t)bid * 64 + w * 16) * DD;
#pragma unroll
  for (int f = 0; f < 8; ++f) {
    const int col = f * 16 + l15;
#pragma unroll
    for (int q = 0; q < 4; ++q) {
      const int row = g * 4 + q;
      pbase[row * DD + col] = acc[f][q];
    }
  }
}

// ---------------------------------------------------------------------------
// Kernel 3: out = (part0 + part1) * 2^-14 + ws_ra   (deterministic reduce)
// ---------------------------------------------------------------------------
__global__ __launch_bounds__(256) void k_reduce(
    const float* __restrict__ part, const float* __restrict__ ws_ra,
    float* __restrict__ out)
{
  const size_t e = ((size_t)blockIdx.x * 256 + threadIdx.x) * 4;
  const int    mblk  = (int)(e >> 13);
  const int    local = (int)(e & 8191);
  const f32x4 p0 = *(const f32x4*)&part[(size_t)(2 * mblk)     * 8192 + local];
  const f32x4 p1 = *(const f32x4*)&part[(size_t)(2 * mblk + 1) * 8192 + local];
  const f32x4 ra = *(const f32x4*)&ws_ra[e];
  f32x4 o;
#pragma unroll
  for (int i = 0; i < 4; ++i) o[i] = (p0[i] + p1[i]) * INV_ASCALE + ra[i];
  *(f32x4*)&out[e] = o;
}

extern "C" void kernel_launch(void* const* d_in, const int* in_sizes, int n_in,
                              void* d_out, int out_size, void* d_ws, size_t ws_size,
                              hipStream_t stream) {
  const float*     h    = (const float*)d_in[0];
  const float*     adj  = (const float*)d_in[1];
  const long long* ridx = (const long long*)d_in[2];   // int64 per reference
  const float*     W    = (const float*)d_in[3];
  const float*     LW   = (const float*)d_in[4];
  const float*     RP   = (const float*)d_in[5];
  const float*     bias = (const float*)d_in[6];
  float* out = (float*)d_out;

  float* ws_ra = (float*)d_ws;                                    // 8 MB @ 0
  void*  tT8   = (void*)((char*)d_ws + (size_t)8  * 1024 * 1024); // 2 MB @ 8M
  float* part  = (float*)((char*)d_ws + (size_t)16 * 1024 * 1024);// 16 MB @ 16M

  hipLaunchKernelGGL(k_small, dim3(NV / 64), dim3(256), 0, stream,
                     h, ridx, W, LW, RP, bias, ws_ra, (i32x2*)tT8);
  hipLaunchKernelGGL(k_big, dim3(NV / 64 * 2), dim3(256), 0, stream,
                     adj, (const unsigned char*)tT8, part);
  hipLaunchKernelGGL(k_reduce, dim3((NV * DD / 4) / 256), dim3(256), 0, stream,
                     part, ws_ra, out);
}